// Round 31
// baseline (147.586 us; speedup 1.0000x reference)
//
#include <hip/hip_runtime.h>
#include <hip/hip_bf16.h>

typedef __attribute__((ext_vector_type(4))) float f32x4;
typedef __attribute__((ext_vector_type(8))) short short8;
typedef __attribute__((ext_vector_type(8))) __bf16 bf16x8;

#define NDIM 172
#define EDIM 172
#define TDIM 100
#define KCAT 444   // 172+172+100
#define QDIM 272   // 172+100
#define ODIM 128
#define ZDIM 256
#define NNBR 32
#define NPH 14     // K=32 phases (448 padded)
#define NT 7       // K=64 tiles
#define RPB 32     // batch rows per block -> grid = 256 = 1 block/CU, persistent
#define LN_EPS 1e-5f

// ---- LDS map (dynamic, ~148 KB, 1 block/CU by design) ----
#define Z_OFF    0         // Z bf16 [128][256] ZB-swizzled (4-row tail groups)
#define A_OFF    65536     // A exchange: single 7-tile slab (28 KB)
#define WOC_OFF  94208     // Wo bf16 c-major, 272 B row pitch (34816 B)
#define QRES_OFF 129024    // [32][128] f32
#define MASK_OFF 145408    // [32][32] int
#define OB_OFF   149504    // [4][128] f32
#define RED_OFF  151552    // [16][2] f32
#define SMEM_BYTES 151680

#define ZB(r,c) ((((r) * 512) + ((c) * 2)) ^ (((r) & 7) << 4))

// lgkm-only barrier: vmcnt (the deep A-load pipeline) stays in flight
#define BARRIER() do { \
    asm volatile("s_waitcnt lgkmcnt(0)\ns_barrier" ::: "memory"); \
    __builtin_amdgcn_sched_barrier(0); \
} while (0)

__device__ __forceinline__ unsigned short f2bf(float f) {
    unsigned u = __builtin_bit_cast(unsigned, f);
    u += 0x7fffu + ((u >> 16) & 1u);
    return (unsigned short)(u >> 16);
}
__device__ __forceinline__ float bf2f(unsigned short h) {
    unsigned u = ((unsigned)h) << 16;
    return __builtin_bit_cast(float, u);
}
__device__ __forceinline__ unsigned short bfb(float f) {
    return __builtin_bit_cast(unsigned short, (__bf16)f);
}

// ---- prep: wfrag = Wkv bf16 in MFMA B-fragment order (R7 layout):
// [phase 0..13][n16 0..15][lane 0..63][8]; row=n16*16+(l&15), k=phase*32+(l>>4)*8+e
#define WFRAG_N (NPH * 8192)        // 114688 shorts
#define WQT_N (QDIM * ODIM)         // 34816
#define WOT_N (ODIM * ODIM)         // 16384
__global__ void prep_pack(const float* __restrict__ Wkv, const float* __restrict__ Wq,
                          const float* __restrict__ Wo,
                          unsigned short* __restrict__ wfrag,
                          unsigned short* __restrict__ wqT,
                          unsigned short* __restrict__ woT) {
    int idx = blockIdx.x * 256 + threadIdx.x;
    if (idx < WFRAG_N) {
        int phase = idx >> 13;
        int r = idx & 8191;
        int n16 = r >> 9;
        int q = r & 511;
        int l = q >> 3, e = q & 7;
        int row = n16 * 16 + (l & 15);
        int k = phase * 32 + ((l >> 4) << 3) + e;
        wfrag[idx] = f2bf(k < KCAT ? Wkv[row * KCAT + k] : 0.f);
    } else if (idx < WFRAG_N + WQT_N) {
        int j = idx - WFRAG_N;
        int k = j >> 7, c = j & 127;
        wqT[j] = f2bf(Wq[c * QDIM + k]);
    } else if (idx < WFRAG_N + WQT_N + WOT_N) {
        int j = idx - WFRAG_N - WQT_N;
        int k = j >> 7, c = j & 127;
        woT[j] = f2bf(Wo[c * ODIM + k]);
    }
}

// ---- Q projection (unchanged, proven)
__global__ __launch_bounds__(256) void q_proj(
    const float* __restrict__ node_feat, const float* __restrict__ time_feat,
    const unsigned short* __restrict__ wqT, const float* __restrict__ bq,
    float* __restrict__ Qbuf) {
    __shared__ float x[8][QDIM];
    const int tid = threadIdx.x;
    const long b0 = (long)blockIdx.x * 8;
    for (int g = tid; g < 8 * QDIM; g += 256) {
        int r = g / QDIM, k = g - r * QDIM;
        x[r][k] = (k < NDIM) ? node_feat[(b0 + r) * NDIM + k]
                             : time_feat[(b0 + r) * TDIM + (k - NDIM)];
    }
    __syncthreads();
    const int c = tid & 127;
    const int rb = (tid >> 7) * 4;
    float s0 = bq[c], s1 = s0, s2 = s0, s3 = s0;
    #pragma unroll 8
    for (int k = 0; k < QDIM; k++) {
        float w = bf2f(wqT[k * 128 + c]);
        s0 += x[rb + 0][k] * w;
        s1 += x[rb + 1][k] * w;
        s2 += x[rb + 2][k] * w;
        s3 += x[rb + 3][k] * w;
    }
    Qbuf[(b0 + rb + 0) * 128 + c] = s0;
    Qbuf[(b0 + rb + 1) * 128 + c] = s1;
    Qbuf[(b0 + rb + 2) * 128 + c] = s2;
    Qbuf[(b0 + rb + 3) * 128 + c] = s3;
}

// ---- fused (converged best): W in registers, A reg-pipelined 7 deep,
// persistent blocks, single 7-tile window, fused scores+PV, vectorized
// out-proj from LDS (c-major, 272B pitch).
__global__ __launch_bounds__(512, 2) void ta_fused(
    const float* __restrict__ edge_feat, const float* __restrict__ nbr_node,
    const float* __restrict__ nbr_time, const int* __restrict__ nbr_mask,
    const float* __restrict__ Qbuf,
    const unsigned short* __restrict__ wfrag, const float* __restrict__ bkv,
    const unsigned short* __restrict__ woT, const float* __restrict__ bo,
    const float* __restrict__ gamma, const float* __restrict__ beta,
    float* __restrict__ out)
{
    extern __shared__ __align__(16) unsigned char smem[];
    float* qresL = (float*)(smem + QRES_OFF);
    int*   maskL = (int*)(smem + MASK_OFF);
    float* Obuf  = (float*)(smem + OB_OFF);
    float* red   = (float*)(smem + RED_OFF);

    const int tid  = threadIdx.x;
    const int lane = tid & 63;
    const int wid  = tid >> 6;          // 0..7 = 32-col band
    const int b0   = blockIdx.x * RPB;

    // ---- one-time staging: masks, Q rows, Wo (c-major, 272B pitch)
    for (int i = tid; i < RPB * NNBR; i += 512)
        maskL[i] = nbr_mask[(long)b0 * NNBR + i];
    for (int i = tid; i < RPB * ODIM; i += 512)
        qresL[i] = Qbuf[(long)b0 * ODIM + i];
    for (int i = tid; i < WOT_N; i += 512) {
        int k = i >> 7, c = i & 127;
        *(unsigned short*)(smem + WOC_OFF + c * 272 + k * 2) = woT[i];
    }
    __syncthreads();   // one-time full drain, nothing deep in flight yet

    // ---- W fragments into registers (one-time; read-only, literal indices)
    bf16x8 Wr[2 * NPH];
    #pragma unroll
    for (int p = 0; p < NPH; p++)
        #pragma unroll
        for (int j = 0; j < 2; j++)
            Wr[p * 2 + j] = __builtin_bit_cast(bf16x8,
                *(const short8*)(wfrag + ((size_t)(p * 16 + wid * 2 + j) * 512 + lane * 8)));
    const float bk0 = bkv[wid * 32 + (lane & 15)];
    const float bk1 = bkv[wid * 32 + 16 + (lane & 15)];
    const float boR = bo[tid & 127];
    const float gmR = gamma[tid & 127];
    const float btR = beta[tid & 127];

    // ---- per-thread A geometry: thread = (rowA 0..31, kgrp 0..15)
    const int rowA  = tid >> 4;
    const int kgrp4 = (tid & 15) * 4;
    const int awb   = ((rowA * 128 + (tid & 15) * 8) ^ ((rowA & 7) << 4));

    // Branch-free A addressing: per-thread pointer + stride tables
    const float* aptr[NT];
    int astr[NT];
    #pragma unroll
    for (int t = 0; t < NT; t++) {
        int k = t * 64 + kgrp4;
        long rg = (long)b0 * NNBR + rowA;
        if (k < NDIM) {
            aptr[t] = nbr_node + rg * NDIM + k;
            astr[t] = NNBR * NDIM;
        } else if (k < NDIM + EDIM) {
            aptr[t] = edge_feat + rg * EDIM + (k - NDIM);
            astr[t] = NNBR * EDIM;
        } else {
            int off = k - NDIM - EDIM;
            if (off > TDIM - 4) off = TDIM - 4;   // pad: garbage x W=0
            aptr[t] = nbr_time + rg * TDIM + off;
            astr[t] = NNBR * TDIM;
        }
    }

    // ---- prologue: iteration 0's 7 tiles in flight (the latency buffer)
    float4 rs[NT];
    #pragma unroll
    for (int t = 0; t < NT; t++) {
        rs[t] = *(const float4*)aptr[t];
        aptr[t] += astr[t];
    }
    __builtin_amdgcn_sched_barrier(0);

    for (int ri = 0; ri < RPB; ri++) {
        f32x4 acc[2][2];
        #pragma unroll
        for (int m = 0; m < 2; m++)
            #pragma unroll
            for (int n = 0; n < 2; n++) acc[m][n] = (f32x4){0.f, 0.f, 0.f, 0.f};

        // ---- stage all 7 tiles (loads issued last ri -> counted vmcnt wait)
        #pragma unroll
        for (int t = 0; t < NT; t++) {
            float4 v = rs[t];
            uint2 u;
            u.x = (unsigned)bfb(v.x) | ((unsigned)bfb(v.y) << 16);
            u.y = (unsigned)bfb(v.z) | ((unsigned)bfb(v.w) << 16);
            *(uint2*)(smem + A_OFF + t * 4096 + awb) = u;
        }
        // rolling refill: iter ri+1, all tiles
        if (ri + 1 < RPB) {
            #pragma unroll
            for (int t = 0; t < NT; t++) {
                rs[t] = *(const float4*)aptr[t];
                aptr[t] += astr[t];
            }
        }
        __builtin_amdgcn_sched_barrier(0);
        BARRIER();                       // slab visible; vmem stays in flight

        // ---- compute all 7 tiles (W from registers)
        __builtin_amdgcn_s_setprio(1);
        #pragma unroll
        for (int t = 0; t < NT; t++) {
            const unsigned char* aw = smem + A_OFF + t * 4096;
            #pragma unroll
            for (int kk = 0; kk < 2; kk++) {
                bf16x8 af[2];
                #pragma unroll
                for (int m = 0; m < 2; m++) {
                    int row = m * 16 + (lane & 15);
                    af[m] = __builtin_bit_cast(bf16x8, *(const short8*)(
                        aw + row * 128 + ((kk * 64 + (lane >> 4) * 16) ^ ((row & 7) << 4))));
                }
                const int p = t * 2 + kk;
                acc[0][0] = __builtin_amdgcn_mfma_f32_16x16x32_bf16(af[0], Wr[p*2+0], acc[0][0], 0, 0, 0);
                acc[0][1] = __builtin_amdgcn_mfma_f32_16x16x32_bf16(af[0], Wr[p*2+1], acc[0][1], 0, 0, 0);
                acc[1][0] = __builtin_amdgcn_mfma_f32_16x16x32_bf16(af[1], Wr[p*2+0], acc[1][0], 0, 0, 0);
                acc[1][1] = __builtin_amdgcn_mfma_f32_16x16x32_bf16(af[1], Wr[p*2+1], acc[1][1], 0, 0, 0);
            }
        }
        __builtin_amdgcn_s_setprio(0);

        // ---- dump Z row-block (+bkv); C/D: col=lane&15, row=(lane>>4)*4+j
        const int gi = ri & 3;
        #pragma unroll
        for (int n = 0; n < 2; n++) {
            int col = wid * 32 + n * 16 + (lane & 15);
            float bk = n ? bk1 : bk0;
            #pragma unroll
            for (int m = 0; m < 2; m++)
                #pragma unroll
                for (int j = 0; j < 4; j++) {
                    int rowZ = gi * 32 + m * 16 + (lane >> 4) * 4 + j;
                    *(unsigned short*)(smem + ZB(rowZ, col)) = bfb(acc[m][n][j] + bk);
                }
        }
        BARRIER();   // slab free for next stage; dumps visible; vmem in flight

        if (gi == 3) {
            const int g = ri >> 2;             // tail group 0..7 (uniform)

            // ---- fused scores + softmax + PV: wave (bl=wid>>1, h=wid&1)
            {
                int bl = wid >> 1, h = wid & 1;
                int n2 = lane >> 1, half = lane & 1;
                int np = h * 16 + (n2 >> 1);
                int rowZ = bl * NNBR + np;
                int cb = (n2 & 1) * 64 + half * 32;
                const float* q = qresL + (g * 4 + bl) * ODIM + h * 64 + half * 32;
                float s = 0.f;
                #pragma unroll
                for (int j = 0; j < 4; j++) {
                    short8 z8 = *(const short8*)(smem + ZB(rowZ, cb + j * 8));
                    #pragma unroll
                    for (int e = 0; e < 8; e++)
                        s += q[j * 8 + e] * bf2f((unsigned short)z8[e]);
                }
                s += __shfl_xor(s, 1);
                s *= 0.125f;
                if (maskL[(g * 4 + bl) * NNBR + n2] == 0) s = -1e10f;
                float mx = s;
                #pragma unroll
                for (int off = 1; off < 64; off <<= 1) mx = fmaxf(mx, __shfl_xor(mx, off));
                float e = __expf(s - mx);
                float sum = e;
                #pragma unroll
                for (int off = 1; off < 64; off <<= 1) sum += __shfl_xor(sum, off);
                float pv = e * 2.f / sum;   // each n2 counted twice in sum

                // PV in-wave: lane d computes O[bl][h*64+d]
                int d = lane;
                float o = 0.f;
                #pragma unroll
                for (int n = 0; n < NNBR; n++) {
                    float p = __shfl(pv, n * 2);
                    int npn = h * 16 + (n >> 1);
                    int col = ODIM + (n & 1) * 64 + d;
                    o += p * bf2f(*(const unsigned short*)(smem + ZB(bl * NNBR + npn, col)));
                }
                Obuf[bl * ODIM + h * 64 + d] = o;
            }
            BARRIER();

            // ---- out proj (vectorized c-major Wo from LDS) + LayerNorm
            {
                int b = tid >> 7, c = tid & 127;
                float s = boR;
                const float* ob = Obuf + b * ODIM;
                const unsigned char* wrow = smem + WOC_OFF + c * 272;
                #pragma unroll
                for (int j = 0; j < 16; j++) {
                    short8 w8 = *(const short8*)(wrow + j * 16);
                    float4 o0 = *(const float4*)(ob + j * 8);
                    float4 o1 = *(const float4*)(ob + j * 8 + 4);
                    s += o0.x * bf2f((unsigned short)w8[0]) + o0.y * bf2f((unsigned short)w8[1])
                       + o0.z * bf2f((unsigned short)w8[2]) + o0.w * bf2f((unsigned short)w8[3])
                       + o1.x * bf2f((unsigned short)w8[4]) + o1.y * bf2f((unsigned short)w8[5])
                       + o1.z * bf2f((unsigned short)w8[6]) + o1.w * bf2f((unsigned short)w8[7]);
                }
                float s1 = s, s2 = s * s;
                #pragma unroll
                for (int off = 1; off < 64; off <<= 1) {
                    s1 += __shfl_xor(s1, off);
                    s2 += __shfl_xor(s2, off);
                }
                if (lane == 0) { red[wid * 2] = s1; red[wid * 2 + 1] = s2; }
                BARRIER();
                float t1 = red[b * 4 + 0] + red[b * 4 + 2];
                float t2 = red[b * 4 + 1] + red[b * 4 + 3];
                float mu  = t1 * (1.f / 128.f);
                float var = t2 * (1.f / 128.f) - mu * mu;
                float inv = rsqrtf(var + LN_EPS);
                out[(long)(b0 + g * 4 + b) * ODIM + c] = (s - mu) * inv * gmR + btR;
            }
            // no end barrier: next Z-dump is >=2 barriers downstream
        }
    }
}

extern "C" void kernel_launch(void* const* d_in, const int* in_sizes, int n_in,
                              void* d_out, int out_size, void* d_ws, size_t ws_size,
                              hipStream_t stream) {
    const float* node_feat = (const float*)d_in[0];
    const float* time_feat = (const float*)d_in[1];
    const float* edge_feat = (const float*)d_in[2];
    const float* nbr_node  = (const float*)d_in[3];
    const float* nbr_time  = (const float*)d_in[4];
    const int*   nbr_mask  = (const int*)d_in[5];
    const float* Wq   = (const float*)d_in[6];
    const float* bq   = (const float*)d_in[7];
    const float* Wkv  = (const float*)d_in[8];
    const float* bkv  = (const float*)d_in[9];
    const float* Wo   = (const float*)d_in[10];
    const float* bo   = (const float*)d_in[11];
    const float* gma  = (const float*)d_in[12];
    const float* bta  = (const float*)d_in[13];
    float* out = (float*)d_out;

    const int B = in_sizes[0] / NDIM;  // 8192

    // workspace layout
    char* ws = (char*)d_ws;
    float* Qbuf = (float*)ws;                                   // B*128*4 = 4 MB
    unsigned short* wfrag = (unsigned short*)(ws + (size_t)B * ODIM * 4);
    unsigned short* wqT   = wfrag + WFRAG_N;
    unsigned short* woT   = wqT + WQT_N;

    hipFuncSetAttribute((const void*)ta_fused,
                        hipFuncAttributeMaxDynamicSharedMemorySize, SMEM_BYTES);

    const int prep_total = WFRAG_N + WQT_N + WOT_N;
    prep_pack<<<dim3((prep_total + 255) / 256), dim3(256), 0, stream>>>(
        Wkv, Wq, Wo, wfrag, wqT, woT);
    q_proj<<<dim3(B / 8), dim3(256), 0, stream>>>(node_feat, time_feat, wqT, bq, Qbuf);
    ta_fused<<<dim3(B / RPB), dim3(512), SMEM_BYTES, stream>>>(
        edge_feat, nbr_node, nbr_time, nbr_mask, Qbuf,
        wfrag, bkv, woT, bo, gma, bta, out);
}

// Round 32
// 147.264 us; speedup vs baseline: 1.0022x; 1.0022x over previous
//
#include <hip/hip_runtime.h>
#include <hip/hip_bf16.h>

typedef __attribute__((ext_vector_type(4))) float f32x4;
typedef __attribute__((ext_vector_type(8))) short short8;
typedef __attribute__((ext_vector_type(8))) __bf16 bf16x8;

#define NDIM 172
#define EDIM 172
#define TDIM 100
#define KCAT 444   // 172+172+100
#define QDIM 272   // 172+100
#define ODIM 128
#define ZDIM 256
#define NNBR 32
#define NPH 14     // K=32 phases (448 padded)
#define NT 7       // K=64 tiles
#define RPB 32     // batch rows per block -> grid = 256 = 1 block/CU, persistent
#define LN_EPS 1e-5f

// ---- LDS map (dynamic, ~148 KB, 1 block/CU by design) ----
#define Z_OFF    0         // Z bf16 [128][256] ZB-swizzled (4-row tail groups)
#define A_OFF    65536     // A exchange: single 7-tile slab (28 KB)
#define WOC_OFF  94208     // Wo bf16 c-major, 272 B row pitch (34816 B)
#define QRES_OFF 129024    // [32][128] f32
#define MASK_OFF 145408    // [32][32] int
#define OB_OFF   149504    // [4][128] f32
#define RED_OFF  151552    // [16][2] f32
#define SMEM_BYTES 151680

#define ZB(r,c) ((((r) * 512) + ((c) * 2)) ^ (((r) & 7) << 4))

// lgkm-only barrier: vmcnt (the deep A-load pipeline) stays in flight
#define BARRIER() do { \
    asm volatile("s_waitcnt lgkmcnt(0)\ns_barrier" ::: "memory"); \
    __builtin_amdgcn_sched_barrier(0); \
} while (0)

__device__ __forceinline__ unsigned short f2bf(float f) {
    unsigned u = __builtin_bit_cast(unsigned, f);
    u += 0x7fffu + ((u >> 16) & 1u);
    return (unsigned short)(u >> 16);
}
__device__ __forceinline__ float bf2f(unsigned short h) {
    unsigned u = ((unsigned)h) << 16;
    return __builtin_bit_cast(float, u);
}
__device__ __forceinline__ unsigned short bfb(float f) {
    return __builtin_bit_cast(unsigned short, (__bf16)f);
}

// ---- prep: wfrag = Wkv bf16 in MFMA B-fragment order (R7 layout):
// [phase 0..13][n16 0..15][lane 0..63][8]; row=n16*16+(l&15), k=phase*32+(l>>4)*8+e
#define WFRAG_N (NPH * 8192)        // 114688 shorts
#define WQT_N (QDIM * ODIM)         // 34816
#define WOT_N (ODIM * ODIM)         // 16384
__global__ void prep_pack(const float* __restrict__ Wkv, const float* __restrict__ Wq,
                          const float* __restrict__ Wo,
                          unsigned short* __restrict__ wfrag,
                          unsigned short* __restrict__ wqT,
                          unsigned short* __restrict__ woT) {
    int idx = blockIdx.x * 256 + threadIdx.x;
    if (idx < WFRAG_N) {
        int phase = idx >> 13;
        int r = idx & 8191;
        int n16 = r >> 9;
        int q = r & 511;
        int l = q >> 3, e = q & 7;
        int row = n16 * 16 + (l & 15);
        int k = phase * 32 + ((l >> 4) << 3) + e;
        wfrag[idx] = f2bf(k < KCAT ? Wkv[row * KCAT + k] : 0.f);
    } else if (idx < WFRAG_N + WQT_N) {
        int j = idx - WFRAG_N;
        int k = j >> 7, c = j & 127;
        wqT[j] = f2bf(Wq[c * QDIM + k]);
    } else if (idx < WFRAG_N + WQT_N + WOT_N) {
        int j = idx - WFRAG_N - WQT_N;
        int k = j >> 7, c = j & 127;
        woT[j] = f2bf(Wo[c * ODIM + k]);
    }
}

// ---- Q projection (unchanged, proven)
__global__ __launch_bounds__(256) void q_proj(
    const float* __restrict__ node_feat, const float* __restrict__ time_feat,
    const unsigned short* __restrict__ wqT, const float* __restrict__ bq,
    float* __restrict__ Qbuf) {
    __shared__ float x[8][QDIM];
    const int tid = threadIdx.x;
    const long b0 = (long)blockIdx.x * 8;
    for (int g = tid; g < 8 * QDIM; g += 256) {
        int r = g / QDIM, k = g - r * QDIM;
        x[r][k] = (k < NDIM) ? node_feat[(b0 + r) * NDIM + k]
                             : time_feat[(b0 + r) * TDIM + (k - NDIM)];
    }
    __syncthreads();
    const int c = tid & 127;
    const int rb = (tid >> 7) * 4;
    float s0 = bq[c], s1 = s0, s2 = s0, s3 = s0;
    #pragma unroll 8
    for (int k = 0; k < QDIM; k++) {
        float w = bf2f(wqT[k * 128 + c]);
        s0 += x[rb + 0][k] * w;
        s1 += x[rb + 1][k] * w;
        s2 += x[rb + 2][k] * w;
        s3 += x[rb + 3][k] * w;
    }
    Qbuf[(b0 + rb + 0) * 128 + c] = s0;
    Qbuf[(b0 + rb + 1) * 128 + c] = s1;
    Qbuf[(b0 + rb + 2) * 128 + c] = s2;
    Qbuf[(b0 + rb + 3) * 128 + c] = s3;
}

// ---- fused (converged best): W in registers, A reg-pipelined 7 deep,
// persistent blocks, single 7-tile window, fused scores+PV, vectorized
// out-proj from LDS (c-major, 272B pitch).
__global__ __launch_bounds__(512, 2) void ta_fused(
    const float* __restrict__ edge_feat, const float* __restrict__ nbr_node,
    const float* __restrict__ nbr_time, const int* __restrict__ nbr_mask,
    const float* __restrict__ Qbuf,
    const unsigned short* __restrict__ wfrag, const float* __restrict__ bkv,
    const unsigned short* __restrict__ woT, const float* __restrict__ bo,
    const float* __restrict__ gamma, const float* __restrict__ beta,
    float* __restrict__ out)
{
    extern __shared__ __align__(16) unsigned char smem[];
    float* qresL = (float*)(smem + QRES_OFF);
    int*   maskL = (int*)(smem + MASK_OFF);
    float* Obuf  = (float*)(smem + OB_OFF);
    float* red   = (float*)(smem + RED_OFF);

    const int tid  = threadIdx.x;
    const int lane = tid & 63;
    const int wid  = tid >> 6;          // 0..7 = 32-col band
    const int b0   = blockIdx.x * RPB;

    // ---- one-time staging: masks, Q rows, Wo (c-major, 272B pitch)
    for (int i = tid; i < RPB * NNBR; i += 512)
        maskL[i] = nbr_mask[(long)b0 * NNBR + i];
    for (int i = tid; i < RPB * ODIM; i += 512)
        qresL[i] = Qbuf[(long)b0 * ODIM + i];
    for (int i = tid; i < WOT_N; i += 512) {
        int k = i >> 7, c = i & 127;
        *(unsigned short*)(smem + WOC_OFF + c * 272 + k * 2) = woT[i];
    }
    __syncthreads();   // one-time full drain, nothing deep in flight yet

    // ---- W fragments into registers (one-time; read-only, literal indices)
    bf16x8 Wr[2 * NPH];
    #pragma unroll
    for (int p = 0; p < NPH; p++)
        #pragma unroll
        for (int j = 0; j < 2; j++)
            Wr[p * 2 + j] = __builtin_bit_cast(bf16x8,
                *(const short8*)(wfrag + ((size_t)(p * 16 + wid * 2 + j) * 512 + lane * 8)));
    const float bk0 = bkv[wid * 32 + (lane & 15)];
    const float bk1 = bkv[wid * 32 + 16 + (lane & 15)];
    const float boR = bo[tid & 127];
    const float gmR = gamma[tid & 127];
    const float btR = beta[tid & 127];

    // ---- per-thread A geometry: thread = (rowA 0..31, kgrp 0..15)
    const int rowA  = tid >> 4;
    const int kgrp4 = (tid & 15) * 4;
    const int awb   = ((rowA * 128 + (tid & 15) * 8) ^ ((rowA & 7) << 4));

    // Branch-free A addressing: per-thread pointer + stride tables
    const float* aptr[NT];
    int astr[NT];
    #pragma unroll
    for (int t = 0; t < NT; t++) {
        int k = t * 64 + kgrp4;
        long rg = (long)b0 * NNBR + rowA;
        if (k < NDIM) {
            aptr[t] = nbr_node + rg * NDIM + k;
            astr[t] = NNBR * NDIM;
        } else if (k < NDIM + EDIM) {
            aptr[t] = edge_feat + rg * EDIM + (k - NDIM);
            astr[t] = NNBR * EDIM;
        } else {
            int off = k - NDIM - EDIM;
            if (off > TDIM - 4) off = TDIM - 4;   // pad: garbage x W=0
            aptr[t] = nbr_time + rg * TDIM + off;
            astr[t] = NNBR * TDIM;
        }
    }

    // ---- prologue: iteration 0's 7 tiles in flight (the latency buffer)
    float4 rs[NT];
    #pragma unroll
    for (int t = 0; t < NT; t++) {
        rs[t] = *(const float4*)aptr[t];
        aptr[t] += astr[t];
    }
    __builtin_amdgcn_sched_barrier(0);

    for (int ri = 0; ri < RPB; ri++) {
        f32x4 acc[2][2];
        #pragma unroll
        for (int m = 0; m < 2; m++)
            #pragma unroll
            for (int n = 0; n < 2; n++) acc[m][n] = (f32x4){0.f, 0.f, 0.f, 0.f};

        // ---- stage all 7 tiles (loads issued last ri -> counted vmcnt wait)
        #pragma unroll
        for (int t = 0; t < NT; t++) {
            float4 v = rs[t];
            uint2 u;
            u.x = (unsigned)bfb(v.x) | ((unsigned)bfb(v.y) << 16);
            u.y = (unsigned)bfb(v.z) | ((unsigned)bfb(v.w) << 16);
            *(uint2*)(smem + A_OFF + t * 4096 + awb) = u;
        }
        // rolling refill: iter ri+1, all tiles
        if (ri + 1 < RPB) {
            #pragma unroll
            for (int t = 0; t < NT; t++) {
                rs[t] = *(const float4*)aptr[t];
                aptr[t] += astr[t];
            }
        }
        __builtin_amdgcn_sched_barrier(0);
        BARRIER();                       // slab visible; vmem stays in flight

        // ---- compute all 7 tiles (W from registers)
        __builtin_amdgcn_s_setprio(1);
        #pragma unroll
        for (int t = 0; t < NT; t++) {
            const unsigned char* aw = smem + A_OFF + t * 4096;
            #pragma unroll
            for (int kk = 0; kk < 2; kk++) {
                bf16x8 af[2];
                #pragma unroll
                for (int m = 0; m < 2; m++) {
                    int row = m * 16 + (lane & 15);
                    af[m] = __builtin_bit_cast(bf16x8, *(const short8*)(
                        aw + row * 128 + ((kk * 64 + (lane >> 4) * 16) ^ ((row & 7) << 4))));
                }
                const int p = t * 2 + kk;
                acc[0][0] = __builtin_amdgcn_mfma_f32_16x16x32_bf16(af[0], Wr[p*2+0], acc[0][0], 0, 0, 0);
                acc[0][1] = __builtin_amdgcn_mfma_f32_16x16x32_bf16(af[0], Wr[p*2+1], acc[0][1], 0, 0, 0);
                acc[1][0] = __builtin_amdgcn_mfma_f32_16x16x32_bf16(af[1], Wr[p*2+0], acc[1][0], 0, 0, 0);
                acc[1][1] = __builtin_amdgcn_mfma_f32_16x16x32_bf16(af[1], Wr[p*2+1], acc[1][1], 0, 0, 0);
            }
        }
        __builtin_amdgcn_s_setprio(0);

        // ---- dump Z row-block (+bkv); C/D: col=lane&15, row=(lane>>4)*4+j
        const int gi = ri & 3;
        #pragma unroll
        for (int n = 0; n < 2; n++) {
            int col = wid * 32 + n * 16 + (lane & 15);
            float bk = n ? bk1 : bk0;
            #pragma unroll
            for (int m = 0; m < 2; m++)
                #pragma unroll
                for (int j = 0; j < 4; j++) {
                    int rowZ = gi * 32 + m * 16 + (lane >> 4) * 4 + j;
                    *(unsigned short*)(smem + ZB(rowZ, col)) = bfb(acc[m][n][j] + bk);
                }
        }
        BARRIER();   // slab free for next stage; dumps visible; vmem in flight

        if (gi == 3) {
            const int g = ri >> 2;             // tail group 0..7 (uniform)

            // ---- fused scores + softmax + PV: wave (bl=wid>>1, h=wid&1)
            {
                int bl = wid >> 1, h = wid & 1;
                int n2 = lane >> 1, half = lane & 1;
                int np = h * 16 + (n2 >> 1);
                int rowZ = bl * NNBR + np;
                int cb = (n2 & 1) * 64 + half * 32;
                const float* q = qresL + (g * 4 + bl) * ODIM + h * 64 + half * 32;
                float s = 0.f;
                #pragma unroll
                for (int j = 0; j < 4; j++) {
                    short8 z8 = *(const short8*)(smem + ZB(rowZ, cb + j * 8));
                    #pragma unroll
                    for (int e = 0; e < 8; e++)
                        s += q[j * 8 + e] * bf2f((unsigned short)z8[e]);
                }
                s += __shfl_xor(s, 1);
                s *= 0.125f;
                if (maskL[(g * 4 + bl) * NNBR + n2] == 0) s = -1e10f;
                float mx = s;
                #pragma unroll
                for (int off = 1; off < 64; off <<= 1) mx = fmaxf(mx, __shfl_xor(mx, off));
                float e = __expf(s - mx);
                float sum = e;
                #pragma unroll
                for (int off = 1; off < 64; off <<= 1) sum += __shfl_xor(sum, off);
                float pv = e * 2.f / sum;   // each n2 counted twice in sum

                // PV in-wave: lane d computes O[bl][h*64+d]
                int d = lane;
                float o = 0.f;
                #pragma unroll
                for (int n = 0; n < NNBR; n++) {
                    float p = __shfl(pv, n * 2);
                    int npn = h * 16 + (n >> 1);
                    int col = ODIM + (n & 1) * 64 + d;
                    o += p * bf2f(*(const unsigned short*)(smem + ZB(bl * NNBR + npn, col)));
                }
                Obuf[bl * ODIM + h * 64 + d] = o;
            }
            BARRIER();

            // ---- out proj (vectorized c-major Wo from LDS) + LayerNorm
            {
                int b = tid >> 7, c = tid & 127;
                float s = boR;
                const float* ob = Obuf + b * ODIM;
                const unsigned char* wrow = smem + WOC_OFF + c * 272;
                #pragma unroll
                for (int j = 0; j < 16; j++) {
                    short8 w8 = *(const short8*)(wrow + j * 16);
                    float4 o0 = *(const float4*)(ob + j * 8);
                    float4 o1 = *(const float4*)(ob + j * 8 + 4);
                    s += o0.x * bf2f((unsigned short)w8[0]) + o0.y * bf2f((unsigned short)w8[1])
                       + o0.z * bf2f((unsigned short)w8[2]) + o0.w * bf2f((unsigned short)w8[3])
                       + o1.x * bf2f((unsigned short)w8[4]) + o1.y * bf2f((unsigned short)w8[5])
                       + o1.z * bf2f((unsigned short)w8[6]) + o1.w * bf2f((unsigned short)w8[7]);
                }
                float s1 = s, s2 = s * s;
                #pragma unroll
                for (int off = 1; off < 64; off <<= 1) {
                    s1 += __shfl_xor(s1, off);
                    s2 += __shfl_xor(s2, off);
                }
                if (lane == 0) { red[wid * 2] = s1; red[wid * 2 + 1] = s2; }
                BARRIER();
                float t1 = red[b * 4 + 0] + red[b * 4 + 2];
                float t2 = red[b * 4 + 1] + red[b * 4 + 3];
                float mu  = t1 * (1.f / 128.f);
                float var = t2 * (1.f / 128.f) - mu * mu;
                float inv = rsqrtf(var + LN_EPS);
                out[(long)(b0 + g * 4 + b) * ODIM + c] = (s - mu) * inv * gmR + btR;
            }
            // no end barrier: next Z-dump is >=2 barriers downstream
        }
    }
}

extern "C" void kernel_launch(void* const* d_in, const int* in_sizes, int n_in,
                              void* d_out, int out_size, void* d_ws, size_t ws_size,
                              hipStream_t stream) {
    const float* node_feat = (const float*)d_in[0];
    const float* time_feat = (const float*)d_in[1];
    const float* edge_feat = (const float*)d_in[2];
    const float* nbr_node  = (const float*)d_in[3];
    const float* nbr_time  = (const float*)d_in[4];
    const int*   nbr_mask  = (const int*)d_in[5];
    const float* Wq   = (const float*)d_in[6];
    const float* bq   = (const float*)d_in[7];
    const float* Wkv  = (const float*)d_in[8];
    const float* bkv  = (const float*)d_in[9];
    const float* Wo   = (const float*)d_in[10];
    const float* bo   = (const float*)d_in[11];
    const float* gma  = (const float*)d_in[12];
    const float* bta  = (const float*)d_in[13];
    float* out = (float*)d_out;

    const int B = in_sizes[0] / NDIM;  // 8192

    // workspace layout
    char* ws = (char*)d_ws;
    float* Qbuf = (float*)ws;                                   // B*128*4 = 4 MB
    unsigned short* wfrag = (unsigned short*)(ws + (size_t)B * ODIM * 4);
    unsigned short* wqT   = wfrag + WFRAG_N;
    unsigned short* woT   = wqT + WQT_N;

    hipFuncSetAttribute((const void*)ta_fused,
                        hipFuncAttributeMaxDynamicSharedMemorySize, SMEM_BYTES);

    const int prep_total = WFRAG_N + WQT_N + WOT_N;
    prep_pack<<<dim3((prep_total + 255) / 256), dim3(256), 0, stream>>>(
        Wkv, Wq, Wo, wfrag, wqT, woT);
    q_proj<<<dim3(B / 8), dim3(256), 0, stream>>>(node_feat, time_feat, wqT, bq, Qbuf);
    ta_fused<<<dim3(B / RPB), dim3(512), SMEM_BYTES, stream>>>(
        edge_feat, nbr_node, nbr_time, nbr_mask, Qbuf,
        wfrag, bkv, woT, bo, gma, bta, out);
}

// Round 33
// 146.393 us; speedup vs baseline: 1.0081x; 1.0060x over previous
//
#include <hip/hip_runtime.h>
#include <hip/hip_bf16.h>

typedef __attribute__((ext_vector_type(4))) float f32x4;
typedef __attribute__((ext_vector_type(8))) short short8;
typedef __attribute__((ext_vector_type(8))) __bf16 bf16x8;

#define NDIM 172
#define EDIM 172
#define TDIM 100
#define KCAT 444   // 172+172+100
#define QDIM 272   // 172+100
#define ODIM 128
#define ZDIM 256
#define NNBR 32
#define NPH 14     // K=32 phases (448 padded)
#define NT 7       // K=64 tiles
#define RPB 32     // batch rows per block -> grid = 256 = 1 block/CU, persistent
#define LN_EPS 1e-5f

// ---- LDS map (dynamic, ~148 KB, 1 block/CU by design) ----
#define Z_OFF    0         // Z bf16 [128][256] ZB-swizzled (4-row tail groups)
#define A_OFF    65536     // A exchange: single 7-tile slab (28 KB)
#define WOC_OFF  94208     // Wo bf16 c-major, 272 B row pitch (34816 B)
#define QRES_OFF 129024    // [32][128] f32
#define MASK_OFF 145408    // [32][32] int
#define OB_OFF   149504    // [4][128] f32
#define RED_OFF  151552    // [16][2] f32
#define SMEM_BYTES 151680

#define ZB(r,c) ((((r) * 512) + ((c) * 2)) ^ (((r) & 7) << 4))

// lgkm-only barrier: vmcnt (the deep A-load pipeline) stays in flight
#define BARRIER() do { \
    asm volatile("s_waitcnt lgkmcnt(0)\ns_barrier" ::: "memory"); \
    __builtin_amdgcn_sched_barrier(0); \
} while (0)

__device__ __forceinline__ unsigned short f2bf(float f) {
    unsigned u = __builtin_bit_cast(unsigned, f);
    u += 0x7fffu + ((u >> 16) & 1u);
    return (unsigned short)(u >> 16);
}
__device__ __forceinline__ float bf2f(unsigned short h) {
    unsigned u = ((unsigned)h) << 16;
    return __builtin_bit_cast(float, u);
}
__device__ __forceinline__ unsigned short bfb(float f) {
    return __builtin_bit_cast(unsigned short, (__bf16)f);
}

// ---- prep: wfrag = Wkv bf16 in MFMA B-fragment order (R7 layout):
// [phase 0..13][n16 0..15][lane 0..63][8]; row=n16*16+(l&15), k=phase*32+(l>>4)*8+e
#define WFRAG_N (NPH * 8192)        // 114688 shorts
#define WQT_N (QDIM * ODIM)         // 34816
#define WOT_N (ODIM * ODIM)         // 16384
__global__ void prep_pack(const float* __restrict__ Wkv, const float* __restrict__ Wq,
                          const float* __restrict__ Wo,
                          unsigned short* __restrict__ wfrag,
                          unsigned short* __restrict__ wqT,
                          unsigned short* __restrict__ woT) {
    int idx = blockIdx.x * 256 + threadIdx.x;
    if (idx < WFRAG_N) {
        int phase = idx >> 13;
        int r = idx & 8191;
        int n16 = r >> 9;
        int q = r & 511;
        int l = q >> 3, e = q & 7;
        int row = n16 * 16 + (l & 15);
        int k = phase * 32 + ((l >> 4) << 3) + e;
        wfrag[idx] = f2bf(k < KCAT ? Wkv[row * KCAT + k] : 0.f);
    } else if (idx < WFRAG_N + WQT_N) {
        int j = idx - WFRAG_N;
        int k = j >> 7, c = j & 127;
        wqT[j] = f2bf(Wq[c * QDIM + k]);
    } else if (idx < WFRAG_N + WQT_N + WOT_N) {
        int j = idx - WFRAG_N - WQT_N;
        int k = j >> 7, c = j & 127;
        woT[j] = f2bf(Wo[c * ODIM + k]);
    }
}

// ---- Q projection (unchanged, proven)
__global__ __launch_bounds__(256) void q_proj(
    const float* __restrict__ node_feat, const float* __restrict__ time_feat,
    const unsigned short* __restrict__ wqT, const float* __restrict__ bq,
    float* __restrict__ Qbuf) {
    __shared__ float x[8][QDIM];
    const int tid = threadIdx.x;
    const long b0 = (long)blockIdx.x * 8;
    for (int g = tid; g < 8 * QDIM; g += 256) {
        int r = g / QDIM, k = g - r * QDIM;
        x[r][k] = (k < NDIM) ? node_feat[(b0 + r) * NDIM + k]
                             : time_feat[(b0 + r) * TDIM + (k - NDIM)];
    }
    __syncthreads();
    const int c = tid & 127;
    const int rb = (tid >> 7) * 4;
    float s0 = bq[c], s1 = s0, s2 = s0, s3 = s0;
    #pragma unroll 8
    for (int k = 0; k < QDIM; k++) {
        float w = bf2f(wqT[k * 128 + c]);
        s0 += x[rb + 0][k] * w;
        s1 += x[rb + 1][k] * w;
        s2 += x[rb + 2][k] * w;
        s3 += x[rb + 3][k] * w;
    }
    Qbuf[(b0 + rb + 0) * 128 + c] = s0;
    Qbuf[(b0 + rb + 1) * 128 + c] = s1;
    Qbuf[(b0 + rb + 2) * 128 + c] = s2;
    Qbuf[(b0 + rb + 3) * 128 + c] = s3;
}

// ---- fused (converged best): W in registers, A reg-pipelined 7 deep,
// persistent blocks, single 7-tile window, fused scores+PV, vectorized
// out-proj from LDS (c-major, 272B pitch).
__global__ __launch_bounds__(512, 2) void ta_fused(
    const float* __restrict__ edge_feat, const float* __restrict__ nbr_node,
    const float* __restrict__ nbr_time, const int* __restrict__ nbr_mask,
    const float* __restrict__ Qbuf,
    const unsigned short* __restrict__ wfrag, const float* __restrict__ bkv,
    const unsigned short* __restrict__ woT, const float* __restrict__ bo,
    const float* __restrict__ gamma, const float* __restrict__ beta,
    float* __restrict__ out)
{
    extern __shared__ __align__(16) unsigned char smem[];
    float* qresL = (float*)(smem + QRES_OFF);
    int*   maskL = (int*)(smem + MASK_OFF);
    float* Obuf  = (float*)(smem + OB_OFF);
    float* red   = (float*)(smem + RED_OFF);

    const int tid  = threadIdx.x;
    const int lane = tid & 63;
    const int wid  = tid >> 6;          // 0..7 = 32-col band
    const int b0   = blockIdx.x * RPB;

    // ---- one-time staging: masks, Q rows, Wo (c-major, 272B pitch)
    for (int i = tid; i < RPB * NNBR; i += 512)
        maskL[i] = nbr_mask[(long)b0 * NNBR + i];
    for (int i = tid; i < RPB * ODIM; i += 512)
        qresL[i] = Qbuf[(long)b0 * ODIM + i];
    for (int i = tid; i < WOT_N; i += 512) {
        int k = i >> 7, c = i & 127;
        *(unsigned short*)(smem + WOC_OFF + c * 272 + k * 2) = woT[i];
    }
    __syncthreads();   // one-time full drain, nothing deep in flight yet

    // ---- W fragments into registers (one-time; read-only, literal indices)
    bf16x8 Wr[2 * NPH];
    #pragma unroll
    for (int p = 0; p < NPH; p++)
        #pragma unroll
        for (int j = 0; j < 2; j++)
            Wr[p * 2 + j] = __builtin_bit_cast(bf16x8,
                *(const short8*)(wfrag + ((size_t)(p * 16 + wid * 2 + j) * 512 + lane * 8)));
    const float bk0 = bkv[wid * 32 + (lane & 15)];
    const float bk1 = bkv[wid * 32 + 16 + (lane & 15)];
    const float boR = bo[tid & 127];
    const float gmR = gamma[tid & 127];
    const float btR = beta[tid & 127];

    // ---- per-thread A geometry: thread = (rowA 0..31, kgrp 0..15)
    const int rowA  = tid >> 4;
    const int kgrp4 = (tid & 15) * 4;
    const int awb   = ((rowA * 128 + (tid & 15) * 8) ^ ((rowA & 7) << 4));

    // Branch-free A addressing: per-thread pointer + stride tables
    const float* aptr[NT];
    int astr[NT];
    #pragma unroll
    for (int t = 0; t < NT; t++) {
        int k = t * 64 + kgrp4;
        long rg = (long)b0 * NNBR + rowA;
        if (k < NDIM) {
            aptr[t] = nbr_node + rg * NDIM + k;
            astr[t] = NNBR * NDIM;
        } else if (k < NDIM + EDIM) {
            aptr[t] = edge_feat + rg * EDIM + (k - NDIM);
            astr[t] = NNBR * EDIM;
        } else {
            int off = k - NDIM - EDIM;
            if (off > TDIM - 4) off = TDIM - 4;   // pad: garbage x W=0
            aptr[t] = nbr_time + rg * TDIM + off;
            astr[t] = NNBR * TDIM;
        }
    }

    // ---- prologue: iteration 0's 7 tiles in flight (the latency buffer)
    float4 rs[NT];
    #pragma unroll
    for (int t = 0; t < NT; t++) {
        rs[t] = *(const float4*)aptr[t];
        aptr[t] += astr[t];
    }
    __builtin_amdgcn_sched_barrier(0);

    for (int ri = 0; ri < RPB; ri++) {
        f32x4 acc[2][2];
        #pragma unroll
        for (int m = 0; m < 2; m++)
            #pragma unroll
            for (int n = 0; n < 2; n++) acc[m][n] = (f32x4){0.f, 0.f, 0.f, 0.f};

        // ---- stage all 7 tiles (loads issued last ri -> counted vmcnt wait)
        #pragma unroll
        for (int t = 0; t < NT; t++) {
            float4 v = rs[t];
            uint2 u;
            u.x = (unsigned)bfb(v.x) | ((unsigned)bfb(v.y) << 16);
            u.y = (unsigned)bfb(v.z) | ((unsigned)bfb(v.w) << 16);
            *(uint2*)(smem + A_OFF + t * 4096 + awb) = u;
        }
        // rolling refill: iter ri+1, all tiles
        if (ri + 1 < RPB) {
            #pragma unroll
            for (int t = 0; t < NT; t++) {
                rs[t] = *(const float4*)aptr[t];
                aptr[t] += astr[t];
            }
        }
        __builtin_amdgcn_sched_barrier(0);
        BARRIER();                       // slab visible; vmem stays in flight

        // ---- compute all 7 tiles (W from registers)
        __builtin_amdgcn_s_setprio(1);
        #pragma unroll
        for (int t = 0; t < NT; t++) {
            const unsigned char* aw = smem + A_OFF + t * 4096;
            #pragma unroll
            for (int kk = 0; kk < 2; kk++) {
                bf16x8 af[2];
                #pragma unroll
                for (int m = 0; m < 2; m++) {
                    int row = m * 16 + (lane & 15);
                    af[m] = __builtin_bit_cast(bf16x8, *(const short8*)(
                        aw + row * 128 + ((kk * 64 + (lane >> 4) * 16) ^ ((row & 7) << 4))));
                }
                const int p = t * 2 + kk;
                acc[0][0] = __builtin_amdgcn_mfma_f32_16x16x32_bf16(af[0], Wr[p*2+0], acc[0][0], 0, 0, 0);
                acc[0][1] = __builtin_amdgcn_mfma_f32_16x16x32_bf16(af[0], Wr[p*2+1], acc[0][1], 0, 0, 0);
                acc[1][0] = __builtin_amdgcn_mfma_f32_16x16x32_bf16(af[1], Wr[p*2+0], acc[1][0], 0, 0, 0);
                acc[1][1] = __builtin_amdgcn_mfma_f32_16x16x32_bf16(af[1], Wr[p*2+1], acc[1][1], 0, 0, 0);
            }
        }
        __builtin_amdgcn_s_setprio(0);

        // ---- dump Z row-block (+bkv); C/D: col=lane&15, row=(lane>>4)*4+j
        const int gi = ri & 3;
        #pragma unroll
        for (int n = 0; n < 2; n++) {
            int col = wid * 32 + n * 16 + (lane & 15);
            float bk = n ? bk1 : bk0;
            #pragma unroll
            for (int m = 0; m < 2; m++)
                #pragma unroll
                for (int j = 0; j < 4; j++) {
                    int rowZ = gi * 32 + m * 16 + (lane >> 4) * 4 + j;
                    *(unsigned short*)(smem + ZB(rowZ, col)) = bfb(acc[m][n][j] + bk);
                }
        }
        BARRIER();   // slab free for next stage; dumps visible; vmem in flight

        if (gi == 3) {
            const int g = ri >> 2;             // tail group 0..7 (uniform)

            // ---- fused scores + softmax + PV: wave (bl=wid>>1, h=wid&1)
            {
                int bl = wid >> 1, h = wid & 1;
                int n2 = lane >> 1, half = lane & 1;
                int np = h * 16 + (n2 >> 1);
                int rowZ = bl * NNBR + np;
                int cb = (n2 & 1) * 64 + half * 32;
                const float* q = qresL + (g * 4 + bl) * ODIM + h * 64 + half * 32;
                float s = 0.f;
                #pragma unroll
                for (int j = 0; j < 4; j++) {
                    short8 z8 = *(const short8*)(smem + ZB(rowZ, cb + j * 8));
                    #pragma unroll
                    for (int e = 0; e < 8; e++)
                        s += q[j * 8 + e] * bf2f((unsigned short)z8[e]);
                }
                s += __shfl_xor(s, 1);
                s *= 0.125f;
                if (maskL[(g * 4 + bl) * NNBR + n2] == 0) s = -1e10f;
                float mx = s;
                #pragma unroll
                for (int off = 1; off < 64; off <<= 1) mx = fmaxf(mx, __shfl_xor(mx, off));
                float e = __expf(s - mx);
                float sum = e;
                #pragma unroll
                for (int off = 1; off < 64; off <<= 1) sum += __shfl_xor(sum, off);
                float pv = e * 2.f / sum;   // each n2 counted twice in sum

                // PV in-wave: lane d computes O[bl][h*64+d]
                int d = lane;
                float o = 0.f;
                #pragma unroll
                for (int n = 0; n < NNBR; n++) {
                    float p = __shfl(pv, n * 2);
                    int npn = h * 16 + (n >> 1);
                    int col = ODIM + (n & 1) * 64 + d;
                    o += p * bf2f(*(const unsigned short*)(smem + ZB(bl * NNBR + npn, col)));
                }
                Obuf[bl * ODIM + h * 64 + d] = o;
            }
            BARRIER();

            // ---- out proj (vectorized c-major Wo from LDS) + LayerNorm
            {
                int b = tid >> 7, c = tid & 127;
                float s = boR;
                const float* ob = Obuf + b * ODIM;
                const unsigned char* wrow = smem + WOC_OFF + c * 272;
                #pragma unroll
                for (int j = 0; j < 16; j++) {
                    short8 w8 = *(const short8*)(wrow + j * 16);
                    float4 o0 = *(const float4*)(ob + j * 8);
                    float4 o1 = *(const float4*)(ob + j * 8 + 4);
                    s += o0.x * bf2f((unsigned short)w8[0]) + o0.y * bf2f((unsigned short)w8[1])
                       + o0.z * bf2f((unsigned short)w8[2]) + o0.w * bf2f((unsigned short)w8[3])
                       + o1.x * bf2f((unsigned short)w8[4]) + o1.y * bf2f((unsigned short)w8[5])
                       + o1.z * bf2f((unsigned short)w8[6]) + o1.w * bf2f((unsigned short)w8[7]);
                }
                float s1 = s, s2 = s * s;
                #pragma unroll
                for (int off = 1; off < 64; off <<= 1) {
                    s1 += __shfl_xor(s1, off);
                    s2 += __shfl_xor(s2, off);
                }
                if (lane == 0) { red[wid * 2] = s1; red[wid * 2 + 1] = s2; }
                BARRIER();
                float t1 = red[b * 4 + 0] + red[b * 4 + 2];
                float t2 = red[b * 4 + 1] + red[b * 4 + 3];
                float mu  = t1 * (1.f / 128.f);
                float var = t2 * (1.f / 128.f) - mu * mu;
                float inv = rsqrtf(var + LN_EPS);
                out[(long)(b0 + g * 4 + b) * ODIM + c] = (s - mu) * inv * gmR + btR;
            }
            // no end barrier: next Z-dump is >=2 barriers downstream
        }
    }
}

extern "C" void kernel_launch(void* const* d_in, const int* in_sizes, int n_in,
                              void* d_out, int out_size, void* d_ws, size_t ws_size,
                              hipStream_t stream) {
    const float* node_feat = (const float*)d_in[0];
    const float* time_feat = (const float*)d_in[1];
    const float* edge_feat = (const float*)d_in[2];
    const float* nbr_node  = (const float*)d_in[3];
    const float* nbr_time  = (const float*)d_in[4];
    const int*   nbr_mask  = (const int*)d_in[5];
    const float* Wq   = (const float*)d_in[6];
    const float* bq   = (const float*)d_in[7];
    const float* Wkv  = (const float*)d_in[8];
    const float* bkv  = (const float*)d_in[9];
    const float* Wo   = (const float*)d_in[10];
    const float* bo   = (const float*)d_in[11];
    const float* gma  = (const float*)d_in[12];
    const float* bta  = (const float*)d_in[13];
    float* out = (float*)d_out;

    const int B = in_sizes[0] / NDIM;  // 8192

    // workspace layout
    char* ws = (char*)d_ws;
    float* Qbuf = (float*)ws;                                   // B*128*4 = 4 MB
    unsigned short* wfrag = (unsigned short*)(ws + (size_t)B * ODIM * 4);
    unsigned short* wqT   = wfrag + WFRAG_N;
    unsigned short* woT   = wqT + WQT_N;

    hipFuncSetAttribute((const void*)ta_fused,
                        hipFuncAttributeMaxDynamicSharedMemorySize, SMEM_BYTES);

    const int prep_total = WFRAG_N + WQT_N + WOT_N;
    prep_pack<<<dim3((prep_total + 255) / 256), dim3(256), 0, stream>>>(
        Wkv, Wq, Wo, wfrag, wqT, woT);
    q_proj<<<dim3(B / 8), dim3(256), 0, stream>>>(node_feat, time_feat, wqT, bq, Qbuf);
    ta_fused<<<dim3(B / RPB), dim3(512), SMEM_BYTES, stream>>>(
        edge_feat, nbr_node, nbr_time, nbr_mask, Qbuf,
        wfrag, bkv, woT, bo, gma, bta, out);
}